// Round 9
// baseline (350.626 us; speedup 1.0000x reference)
//
#include <hip/hip_runtime.h>
#include <cstddef>

#define H_ 256
#define W_ 256
#define HW_ 65536

typedef unsigned int uint;
typedef unsigned short ushort;
typedef __attribute__((ext_vector_type(8))) short short8;
typedef __attribute__((ext_vector_type(16))) float floatx16;

__device__ __forceinline__ float bf2f(ushort u) {
    return __uint_as_float(((uint)u) << 16);
}
__device__ __forceinline__ ushort f2bf(float f) {
    uint u = __float_as_uint(f);
    uint r = (u + 0x7fffu + ((u >> 16) & 1u)) >> 16;
    return (ushort)r;
}
__device__ __forceinline__ float sigmoidf_(float x) {
    return 1.0f / (1.0f + expf(-x));
}

// async global->LDS, 16B per lane. LDS dest is wave-uniform base + lane*16;
// all staging below keeps per-wave destinations contiguous by construction.
#define GLOAD_LDS16(gsrc, ldst)                                                   \
    __builtin_amdgcn_global_load_lds(                                             \
        (const __attribute__((address_space(1))) void*)(gsrc),                    \
        (__attribute__((address_space(3))) void*)(ldst), 16, 0, 0)

// LDS per buffer: input tile only (1360 used of 1408 slots, 10x34 halo).
// Weights now live in REGISTERS (R9): 18 fragments x 16 B/lane per chunk,
// double-buffered across the chunk loop. This removes 18 of 42 ds_read_b128
// per wave per chunk — the LDS read pipe (~31 us/CU) was the R8 critical pipe.
#define IN_SLOTS 1408

// ============ weight prep: OIHW fp32 -> MFMA-fragment-ordered bf16 ============
__device__ __forceinline__ void prep_one(const float* src, ushort* dst,
                                         int CO, int CI, int e) {
    int chunk = e / 9216;
    int r = e - chunk * 9216;
    int co = r / 288;
    int kk = r - co * 288;
    int khw = kk >> 5;
    int ci = kk & 31;
    int cig = chunk * 32 + ci;
    float v = 0.f;
    if (co < CO && cig < CI) v = src[(co * CI + cig) * 9 + khw];
    int s = kk >> 4;
    int lane = ((kk >> 3) & 1) * 32 + co;
    int j = kk & 7;
    dst[(((size_t)chunk * 18 + s) * 64 + lane) * 8 + j] = f2bf(v);
}

__global__ __launch_bounds__(256) void prep_weights(
    const float* __restrict__ w_in, const float* __restrict__ w2,
    const float* __restrict__ w3, const float* __restrict__ aw1,
    const float* __restrict__ aw2,
    ushort* __restrict__ w_inB, ushort* __restrict__ w2B,
    ushort* __restrict__ w3B, ushort* __restrict__ aw1B,
    ushort* __restrict__ aw2B, ushort* __restrict__ zp) {
    int idx = blockIdx.x * 256 + threadIdx.x;
    if (idx < 64) zp[idx] = 0;
    if (idx < 9216)        prep_one(w_in, w_inB, 32, 32, idx);
    else if (idx < 46080)  prep_one(w2, w2B, 32, 128, idx - 9216);
    else if (idx < 82944)  prep_one(w3, w3B, 32, 128, idx - 46080);
    else if (idx < 92160)  prep_one(aw1, aw1B, 16, 32, idx - 82944);
    else if (idx < 101376) prep_one(aw2, aw2B, 16, 16, idx - 92160);
}

// ============ x: NCHW fp32 -> NHWC bf16 (32 ch) ============
__global__ __launch_bounds__(256) void transform_x(const float* __restrict__ x,
                                                   ushort* __restrict__ xh) {
    __shared__ float s[64][33];
    const int t = threadIdx.x;
    const int w0 = blockIdx.x * 64, h = blockIdx.y, b = blockIdx.z;
    {
        int ww = t & 63, c0 = (t >> 6) * 8;
#pragma unroll
        for (int j = 0; j < 8; j++) {
            int c = c0 + j;
            s[ww][c] = x[((size_t)(b * 32 + c)) * HW_ + h * W_ + w0 + ww];
        }
    }
    __syncthreads();
    {
        int p = t >> 2, cb = t & 3;
        ushort tmp[8];
#pragma unroll
        for (int j = 0; j < 8; j++) tmp[j] = f2bf(s[p][cb * 8 + j]);
        *(uint4*)(xh + (((size_t)b * HW_ + h * W_ + w0 + p) * 32) + cb * 8) =
            *(const uint4*)tmp;
    }
}

// ---- staging descriptor for direct-to-LDS path (32x8 tile, 10x34 halo) ------
// LDS layout LINEAR in slot u (global_load_lds requirement). The XOR
// bank-swizzle is realized by inverse-swizzling the GLOBAL source address:
// linear slot (row,p,q) receives channel-block cb = q ^ swz(p) (involution), so
// the read-side swizzled addressing in mfma_chunk is unchanged.
// 1360 valid slots: rounds 0..4 full (u=i*256+t), round 5 = waves 0,1 only
// (u = 1280+t, t<128; slots 1360..1407 are zero-pad).
struct StageDescL {
    uint goff[6];
    bool ok[6];
};
__device__ __forceinline__ void make_descL(StageDescL& d, int t, int w0, int h0, int b) {
#pragma unroll
    for (int i = 0; i < 6; i++) {
        int u = (i < 5) ? (i * 256 + t) : (1280 + t);
        int row = u / 136;
        int rem = u - row * 136;
        int p = rem >> 2, q = rem & 3;
        int cb = q ^ (p & 3) ^ ((p >> 2) & 3);
        int gh = h0 - 1 + row, gw = w0 - 1 + p;
        d.ok[i] = (u < 1360) && ((unsigned)gh < 256u) && ((unsigned)gw < 256u);
        d.goff[i] = d.ok[i] ? (((uint)b * HW_ + (uint)gh * W_ + (uint)gw) * 32 + cb * 8) : 0u;
    }
}
// input stage: 5 full rounds + tail (waves 0,1). 6 DMAs for waves 0,1; 5 for 2,3.
__device__ __forceinline__ void stage_input(ushort* ibuf, const StageDescL& d,
                                            const ushort* __restrict__ inp,
                                            const ushort* __restrict__ zp,
                                            int t, int wid) {
#pragma unroll
    for (int i = 0; i < 5; i++) {
        const ushort* src = d.ok[i] ? (inp + d.goff[i]) : zp;
        GLOAD_LDS16(src, ibuf + (size_t)(i * 256 + t) * 8);
    }
    if (wid < 2) {  // wave-uniform tail: slots 1280..1407
        const ushort* src = d.ok[5] ? (inp + d.goff[5]) : zp;
        GLOAD_LDS16(src, ibuf + (size_t)(1280 + t) * 8);
    }
}
// weight load: 18 fragments (16 B/lane each) into registers, coalesced
// 1 KB/instruction. Issued in the STAGE phase so the counted vmcnt covers
// them and the MFMA phase stays free of VMEM ops.
__device__ __forceinline__ void load_wregs(short8* w,
                                           const ushort* __restrict__ wsrc,
                                           int lane) {
#pragma unroll
    for (int s = 0; s < 18; s++)
        w[s] = *(const short8*)(wsrc + (size_t)(s * 64 + lane) * 8);
}

// MFMA phase over one staged chunk — PURE LDS + MFMA (zero VMEM ops, so no
// vmcnt wait can be emitted here and prefetch DMAs/loads stay in flight).
// Weights come from registers: 24 ds_read_b128/wave/chunk (was 42).
__device__ __forceinline__ void mfma_chunk(const ushort* ibuf, const short8* w,
                                           int lco, int lhalf, int wid,
                                           floatx16& acc0, floatx16& acc1) {
#pragma unroll
    for (int half = 0; half < 2; half++) {
        const int cbr = half * 2 + lhalf;
#pragma unroll
        for (int kw = 0; kw < 3; kw++) {
            const int ww = lco + kw;
            const int cbs = cbr ^ (ww & 3) ^ ((ww >> 2) & 3);
            short8 a[4];
#pragma unroll
            for (int r = 0; r < 4; r++)
                a[r] = *(const short8*)(ibuf + (size_t)((wid * 2 + r) * 136 + (ww << 2) + cbs) * 8);
#pragma unroll
            for (int kh = 0; kh < 3; kh++) {
                acc0 = __builtin_amdgcn_mfma_f32_32x32x16_bf16(
                    a[kh], w[2 * (kh * 3 + kw) + half], acc0, 0, 0, 0);
                acc1 = __builtin_amdgcn_mfma_f32_32x32x16_bf16(
                    a[kh + 1], w[2 * (kh * 3 + kw) + half], acc1, 0, 0, 0);
            }
        }
    }
}

// ============ unified conv 3x3 (implicit GEMM, MFMA 32x32x16) =================
// T3/T4 pipeline, register-weight edition: per chunk per wave the stage phase
// issues {6|5 input DMAs + 18 weight reg-loads}; raw s_barrier + wave-uniform
// counted s_waitcnt vmcnt(24|23) keeps chunk ch+1's batch in flight across
// chunk ch's entire MFMA phase. Weight regs are double-buffered (144 VGPRs);
// __launch_bounds__(256,2) caps at 256 VGPR — watch WRITE_SIZE for spill.
template<int NCHUNK, int EPI, bool RELU>
__global__ __launch_bounds__(256, (NCHUNK > 1) ? 2 : 3) void conv_mfma(
    const ushort* __restrict__ in0, const ushort* __restrict__ in1,
    const ushort* __restrict__ in2, const ushort* __restrict__ in3,
    const ushort* __restrict__ wB, const ushort* __restrict__ zp,
    ushort* __restrict__ outp, const float* __restrict__ aux_w,
    const float* __restrict__ aux_b) {
    constexpr int NBUF = (NCHUNK > 1) ? 2 : 1;
    __shared__ __align__(16) ushort smem[NBUF][IN_SLOTS * 8];  // 22.5 KB / buf
    const int t = threadIdx.x;
    const int wid = t >> 6;
    const int lane = t & 63;
    const int lco = lane & 31, lhalf = lane >> 5;
    const int w0 = blockIdx.x * 32, h0 = blockIdx.y * 8, b = blockIdx.z;
    const ushort* ins[4] = {in0, in1, in2, in3};

    StageDescL d;
    make_descL(d, t, w0, h0, b);

    floatx16 acc0, acc1;
#pragma unroll
    for (int i = 0; i < 16; i++) { acc0[i] = 0.f; acc1[i] = 0.f; }

    short8 wr0[18], wr1[18];
    stage_input(smem[0], d, ins[0], zp, t, wid);
    load_wregs(wr0, wB, lane);

    if constexpr (NCHUNK == 1) {
        __syncthreads();
        mfma_chunk(smem[0], wr0, lco, lhalf, wid, acc0, acc1);
    } else {
#pragma unroll
        for (int ch = 0; ch < NCHUNK; ch++) {
            // barrier A: all waves' LDS reads of buf[(ch+1)&1] (chunk ch-1) done
            asm volatile("s_waitcnt lgkmcnt(0)" ::: "memory");
            __builtin_amdgcn_s_barrier();
            if (ch + 1 < NCHUNK) {
                stage_input(smem[(ch + 1) & 1], d, ins[ch + 1], zp, t, wid);
                load_wregs(((ch + 1) & 1) ? wr1 : wr0,
                           wB + (size_t)(ch + 1) * 9216, lane);
                // leave exactly chunk ch+1's batch in flight (wave-uniform)
                if (wid < 2) asm volatile("s_waitcnt vmcnt(24)" ::: "memory");
                else         asm volatile("s_waitcnt vmcnt(23)" ::: "memory");
            } else {
                asm volatile("s_waitcnt vmcnt(0)" ::: "memory");
            }
            __builtin_amdgcn_s_barrier();  // barrier B: buf[ch] staged everywhere
            mfma_chunk(smem[ch & 1], (ch & 1) ? wr1 : wr0,
                       lco, lhalf, wid, acc0, acc1);
        }
    }

    if (EPI == 0) {
        // direct stores: per r the wave writes two contiguous 64B runs
#pragma unroll
        for (int r = 0; r < 16; r++) {
            int wl = (r & 3) + 8 * (r >> 2) + 4 * lhalf;
            float v0 = acc0[r], v1 = acc1[r];
            if (RELU) { v0 = fmaxf(v0, 0.f); v1 = fmaxf(v1, 0.f); }
            size_t p0 = (((size_t)b * HW_ + (h0 + wid * 2) * W_ + w0 + wl) * 32) + lco;
            outp[p0] = f2bf(v0);
            outp[p0 + (size_t)W_ * 32] = f2bf(v1);
        }
    } else {
        __syncthreads();  // smem free for epilogue tile [pix 256][stride 40]
        ushort* ep = &smem[0][0];
#pragma unroll
        for (int r = 0; r < 16; r++) {
            int wl = (r & 3) + 8 * (r >> 2) + 4 * lhalf;
            float v0 = acc0[r], v1 = acc1[r];
            if (RELU) { v0 = fmaxf(v0, 0.f); v1 = fmaxf(v1, 0.f); }
            int pix0 = (wid * 2) * 32 + wl;
            ep[(size_t)pix0 * 40 + lco] = f2bf(v0);
            ep[(size_t)(pix0 + 32) * 40 + lco] = f2bf(v1);
        }
        __syncthreads();
        const ushort* tp = ep + (size_t)t * 40;
        if (EPI == 1) {
            float xin[16];
            uint4 q0 = *(const uint4*)tp;
            uint4 q1 = *(const uint4*)(tp + 8);
            const ushort* u0 = (const ushort*)&q0;
            const ushort* u1 = (const ushort*)&q1;
#pragma unroll
            for (int j = 0; j < 8; j++) { xin[j] = bf2f(u0[j]); xin[8 + j] = bf2f(u1[j]); }
            size_t pix = (size_t)b * HW_ + (size_t)(h0 + (t >> 5)) * W_ + w0 + (t & 31);
#pragma unroll
            for (int g = 0; g < 4; g++) {
                float acc = aux_b[g];
#pragma unroll
                for (int ci = 0; ci < 16; ci++) acc = fmaf(xin[ci], aux_w[g * 16 + ci], acc);
                outp[(size_t)g * 8 * HW_ + pix] = f2bf(sigmoidf_(acc));
            }
        } else {
            float acc = 0.f;
#pragma unroll
            for (int q = 0; q < 4; q++) {
                uint4 qv = *(const uint4*)(tp + q * 8);
                const ushort* uq = (const ushort*)&qv;
#pragma unroll
                for (int j = 0; j < 8; j++) acc = fmaf(bf2f(uq[j]), aux_w[q * 8 + j], acc);
            }
            float* fo = (float*)outp;
            fo[(size_t)b * HW_ + (size_t)(h0 + (t >> 5)) * W_ + w0 + (t & 31)] = sigmoidf_(acc);
        }
    }
}

// ============ dual conv: one staging of xh -> feat (w_in) + a1 (aw1, relu) ====
// Single weight reg buffer, reloaded between the two mfma passes (register
// dependency serializes the reload; ~one load latency exposed once per block).
__global__ __launch_bounds__(256, 2) void conv_dual(
    const ushort* __restrict__ in0, const ushort* __restrict__ wBa,
    const ushort* __restrict__ wBb, const ushort* __restrict__ zp,
    ushort* __restrict__ outA, ushort* __restrict__ outB) {
    __shared__ __align__(16) ushort smem[IN_SLOTS * 8];  // 22.5 KB
    const int t = threadIdx.x;
    const int wid = t >> 6;
    const int lane = t & 63;
    const int lco = lane & 31, lhalf = lane >> 5;
    const int w0 = blockIdx.x * 32, h0 = blockIdx.y * 8, b = blockIdx.z;

    StageDescL d;
    make_descL(d, t, w0, h0, b);

    floatx16 accA0, accA1, accB0, accB1;
#pragma unroll
    for (int i = 0; i < 16; i++) { accA0[i] = 0.f; accA1[i] = 0.f; accB0[i] = 0.f; accB1[i] = 0.f; }

    short8 wr[18];
    stage_input(smem, d, in0, zp, t, wid);
    load_wregs(wr, wBa, lane);
    __syncthreads();
    mfma_chunk(smem, wr, lco, lhalf, wid, accA0, accA1);
    load_wregs(wr, wBb, lane);
    mfma_chunk(smem, wr, lco, lhalf, wid, accB0, accB1);

#pragma unroll
    for (int r = 0; r < 16; r++) {
        int wl = (r & 3) + 8 * (r >> 2) + 4 * lhalf;
        size_t p0 = (((size_t)b * HW_ + (h0 + wid * 2) * W_ + w0 + wl) * 32) + lco;
        outA[p0] = f2bf(accA0[r]);
        outA[p0 + (size_t)W_ * 32] = f2bf(accA1[r]);
        outB[p0] = f2bf(fmaxf(accB0[r], 0.f));
        outB[p0 + (size_t)W_ * 32] = f2bf(fmaxf(accB1[r], 0.f));
    }
}

// ============ segmented IRNN scan, vectorized 8ch/thread (R6 form) ============
// Fused fwd+bwd: one block runs the forward pass (seg s) then the backward
// pass (seg 7-s) over the SAME physical 48-row window [32s-8, 32s+40) — the
// second pass's reads hit L2/L3 (reuse distance <= 160 KB), halving per-axis
// cold read traffic vs direction-split blocks. Sequential (NOT interleaved:
// R7 measured interleaving +10 MB write amplification, net negative).
// 8 segments of 32 + 8-step warmup (0.2^8 ~ 2.6e-6, validated in R5).
template<int VERT>
__device__ __forceinline__ void scan_body(
    const ushort* __restrict__ feat, const float* __restrict__ alpha,
    const ushort* __restrict__ wmapT, ushort* __restrict__ gfwd,
    ushort* __restrict__ gbwd, int gf, int gb, int dir, int seg,
    int cgp, int b, int t) {
    const int cg = t & 3;
    const int col = cgp * 64 + (t >> 2);
    const int c0 = cg * 8;

    float a[8];
#pragma unroll
    for (int j = 0; j < 8; j++) a[j] = alpha[c0 + j];

    const ushort* wplane = wmapT + (size_t)(dir ? gb : gf) * 8 * HW_ + (size_t)b * HW_;
    ushort* gout = dir ? gbwd : gfwd;

    const int main0 = seg * 32;
    const int start = (seg == 0) ? 0 : main0 - 8;
    const int cnt = main0 - start + 32;

    auto pixof = [&](int p) -> size_t {
        int phys = dir ? 255 - p : p;
        return VERT ? ((size_t)phys * W_ + col) : ((size_t)col * W_ + phys);
    };

    uint4 xv[4];
    ushort wv[4];
#pragma unroll
    for (int k = 0; k < 4; k++) {
        size_t pix = pixof(start + k);
        xv[k] = *(const uint4*)(feat + ((size_t)b * HW_ + pix) * 32 + c0);
        wv[k] = wplane[pix];
    }
    float prev[8];
#pragma unroll
    for (int j = 0; j < 8; j++) prev[j] = 0.f;

    for (int i = 0; i < cnt; i += 4) {
#pragma unroll
        for (int k = 0; k < 4; k++) {
            const int p = start + i + k;
            uint4 xcur = xv[k];
            ushort wcur = wv[k];
            if (i + k + 4 < cnt) {
                size_t pix = pixof(p + 4);
                xv[k] = *(const uint4*)(feat + ((size_t)b * HW_ + pix) * 32 + c0);
                wv[k] = wplane[pix];
            }
            const ushort* xu = (const ushort*)&xcur;
            if (p >= main0) {
                float wmv = bf2f(wcur);
                ushort o[8];
#pragma unroll
                for (int j = 0; j < 8; j++) {
                    float cur = fmaxf(fmaf(a[j], prev[j], bf2f(xu[j])), 0.f);
                    prev[j] = cur;
                    o[j] = f2bf(cur * wmv);
                }
                *(uint4*)(gout + ((size_t)b * HW_ + pixof(p)) * 32 + c0) = *(const uint4*)o;
            } else {
#pragma unroll
                for (int j = 0; j < 8; j++)
                    prev[j] = fmaxf(fmaf(a[j], prev[j], bf2f(xu[j])), 0.f);
            }
        }
    }
}

__global__ __launch_bounds__(256) void scan_both(
    const ushort* __restrict__ feat, const float* __restrict__ alpha,
    const ushort* __restrict__ wmapT, ushort* __restrict__ g0,
    ushort* __restrict__ g1, ushort* __restrict__ g2, ushort* __restrict__ g3) {
    const int bx = blockIdx.x & 255;
    const int cgp = bx & 3;
    const int seg = (bx >> 2) & 7;
    const int b = bx >> 5;
    const int t = threadIdx.x;
    if (blockIdx.x < 256) {
        // vertical axis: fwd seg s, then bwd seg 7-s (same phys rows)
        scan_body<1>(feat, alpha, wmapT, g0, g2, 0, 2, 0, seg, cgp, b, t);
        scan_body<1>(feat, alpha, wmapT, g0, g2, 0, 2, 1, 7 - seg, cgp, b, t);
    } else {
        scan_body<0>(feat, alpha, wmapT, g1, g3, 1, 3, 0, seg, cgp, b, t);
        scan_body<0>(feat, alpha, wmapT, g1, g3, 1, 3, 1, 7 - seg, cgp, b, t);
    }
}

extern "C" void kernel_launch(void* const* d_in, const int* in_sizes, int n_in,
                              void* d_out, int out_size, void* d_ws, size_t ws_size,
                              hipStream_t stream) {
    const float* x      = (const float*)d_in[0];
    const float* alpha1 = (const float*)d_in[1];
    const float* alpha2 = (const float*)d_in[2];
    const float* w_in   = (const float*)d_in[3];
    const float* w2     = (const float*)d_in[4];
    const float* w3     = (const float*)d_in[5];
    const float* aw1    = (const float*)d_in[6];
    const float* aw2    = (const float*)d_in[7];
    const float* aw3    = (const float*)d_in[8];
    const float* ab3    = (const float*)d_in[9];
    const float* wout   = (const float*)d_in[10];
    float* out = (float*)d_out;

    // ---- workspace carve (ushorts), ~206 MB ----
    const size_t TEN = (size_t)8 * HW_ * 32;
    ushort* p = (ushort*)d_ws;
    ushort* xh    = p; p += TEN;
    ushort* feat  = p; p += TEN;
    ushort* g0    = p; p += TEN;
    ushort* g1    = p; p += TEN;
    ushort* g2    = p; p += TEN;
    ushort* g3    = p; p += TEN;
    ushort* wmapT = p; p += (size_t)4 * 8 * HW_;
    ushort* w_inB = p; p += 9216;
    ushort* w2B   = p; p += 36864;
    ushort* w3B   = p; p += 36864;
    ushort* aw1B  = p; p += 9216;
    ushort* aw2B  = p; p += 9216;
    ushort* zp    = p; p += 64;
    ushort* a1z   = g1;  // attention intermediate overlays g1 (dead until scans)

    prep_weights<<<396, 256, 0, stream>>>(w_in, w2, w3, aw1, aw2,
                                          w_inB, w2B, w3B, aw1B, aw2B, zp);
    transform_x<<<dim3(4, 256, 8), 256, 0, stream>>>(x, xh);

    dim3 gconv(8, 32, 8);  // 32x8 tiles

    // trunk conv + first attention conv share one staging pass of xh
    conv_dual<<<gconv, 256, 0, stream>>>(xh, w_inB, aw1B, zp, feat, a1z);
    // second attention conv with fused att1x1+sigmoid -> wmapT planes
    conv_mfma<1, 1, true><<<gconv, 256, 0, stream>>>(a1z, a1z, a1z, a1z, aw2B, zp,
                                                     wmapT, aw3, ab3);

    // round 1 scans (both axes + both dirs fused, one dispatch)
    scan_both<<<512, 256, 0, stream>>>(feat, alpha1, wmapT, g0, g1, g2, g3);

    conv_mfma<4, 0, false><<<gconv, 256, 0, stream>>>(g0, g1, g2, g3, w2B, zp,
                                                      feat, nullptr, nullptr);

    // round 2 scans
    scan_both<<<512, 256, 0, stream>>>(feat, alpha2, wmapT, g0, g1, g2, g3);

    // final conv with fused out1x1+sigmoid -> fp32 out
    conv_mfma<4, 2, true><<<gconv, 256, 0, stream>>>(g0, g1, g2, g3, w3B, zp,
                                                     (ushort*)out, wout, nullptr);
}

// Round 10
// 339.443 us; speedup vs baseline: 1.0329x; 1.0329x over previous
//
#include <hip/hip_runtime.h>
#include <cstddef>

#define H_ 256
#define W_ 256
#define HW_ 65536

typedef unsigned int uint;
typedef unsigned short ushort;
typedef __attribute__((ext_vector_type(8))) short short8;
typedef __attribute__((ext_vector_type(16))) float floatx16;

__device__ __forceinline__ float bf2f(ushort u) {
    return __uint_as_float(((uint)u) << 16);
}
__device__ __forceinline__ ushort f2bf(float f) {
    uint u = __float_as_uint(f);
    uint r = (u + 0x7fffu + ((u >> 16) & 1u)) >> 16;
    return (ushort)r;
}
__device__ __forceinline__ float sigmoidf_(float x) {
    return 1.0f / (1.0f + expf(-x));
}

// async global->LDS, 16B per lane. LDS dest is wave-uniform base + lane*16;
// all staging below keeps per-wave destinations contiguous by construction.
#define GLOAD_LDS16(gsrc, ldst)                                                   \
    __builtin_amdgcn_global_load_lds(                                             \
        (const __attribute__((address_space(1))) void*)(gsrc),                    \
        (__attribute__((address_space(3))) void*)(ldst), 16, 0, 0)

// LDS slot layout per buffer (slot = 16 B):
//   [0, 1408)    input tile (1360 used, 10x34 halo, rest pad)
//   [1408, 2560) weight fragments for this chunk (18 frag x 64 lanes)
// (R9 lesson: weights belong in LDS — shared DMA once per block beats 4x
// per-wave register fetch through L2.)
#define IN_SLOTS 1408
#define W_SLOTS 1152
#define BUF_SLOTS 2560

// ============ weight prep: OIHW fp32 -> MFMA-fragment-ordered bf16 ============
__device__ __forceinline__ void prep_one(const float* src, ushort* dst,
                                         int CO, int CI, int e) {
    int chunk = e / 9216;
    int r = e - chunk * 9216;
    int co = r / 288;
    int kk = r - co * 288;
    int khw = kk >> 5;
    int ci = kk & 31;
    int cig = chunk * 32 + ci;
    float v = 0.f;
    if (co < CO && cig < CI) v = src[(co * CI + cig) * 9 + khw];
    int s = kk >> 4;
    int lane = ((kk >> 3) & 1) * 32 + co;
    int j = kk & 7;
    dst[(((size_t)chunk * 18 + s) * 64 + lane) * 8 + j] = f2bf(v);
}

__global__ __launch_bounds__(256) void prep_weights(
    const float* __restrict__ w_in, const float* __restrict__ w2,
    const float* __restrict__ w3, const float* __restrict__ aw1,
    const float* __restrict__ aw2,
    ushort* __restrict__ w_inB, ushort* __restrict__ w2B,
    ushort* __restrict__ w3B, ushort* __restrict__ aw1B,
    ushort* __restrict__ aw2B, ushort* __restrict__ zp) {
    int idx = blockIdx.x * 256 + threadIdx.x;
    if (idx < 64) zp[idx] = 0;
    if (idx < 9216)        prep_one(w_in, w_inB, 32, 32, idx);
    else if (idx < 46080)  prep_one(w2, w2B, 32, 128, idx - 9216);
    else if (idx < 82944)  prep_one(w3, w3B, 32, 128, idx - 46080);
    else if (idx < 92160)  prep_one(aw1, aw1B, 16, 32, idx - 82944);
    else if (idx < 101376) prep_one(aw2, aw2B, 16, 16, idx - 92160);
}

// ============ x: NCHW fp32 -> NHWC bf16 (32 ch) ============
__global__ __launch_bounds__(256) void transform_x(const float* __restrict__ x,
                                                   ushort* __restrict__ xh) {
    __shared__ float s[64][33];
    const int t = threadIdx.x;
    const int w0 = blockIdx.x * 64, h = blockIdx.y, b = blockIdx.z;
    {
        int ww = t & 63, c0 = (t >> 6) * 8;
#pragma unroll
        for (int j = 0; j < 8; j++) {
            int c = c0 + j;
            s[ww][c] = x[((size_t)(b * 32 + c)) * HW_ + h * W_ + w0 + ww];
        }
    }
    __syncthreads();
    {
        int p = t >> 2, cb = t & 3;
        ushort tmp[8];
#pragma unroll
        for (int j = 0; j < 8; j++) tmp[j] = f2bf(s[p][cb * 8 + j]);
        *(uint4*)(xh + (((size_t)b * HW_ + h * W_ + w0 + p) * 32) + cb * 8) =
            *(const uint4*)tmp;
    }
}

// ---- staging descriptor for direct-to-LDS path (32x8 tile, 10x34 halo) ------
// LDS layout LINEAR in slot u (global_load_lds requirement). The XOR
// bank-swizzle is realized by inverse-swizzling the GLOBAL source address:
// linear slot (row,p,q) receives channel-block cb = q ^ swz(p) (involution), so
// the read-side swizzled addressing in mfma_chunk is unchanged.
// goffT: source address for TRANSPOSED inputs (g1/g3 stored h<->w swapped so
// the horizontal scan writes coalesced; logical g(h,w) lives at gT[w*W+h]).
// 1360 valid slots: rounds 0..4 full (u=i*256+t), round 5 = waves 0,1 only.
struct StageDescL {
    uint goff[6];
    uint goffT[6];
    bool ok[6];
};
__device__ __forceinline__ void make_descL(StageDescL& d, int t, int w0, int h0, int b) {
#pragma unroll
    for (int i = 0; i < 6; i++) {
        int u = (i < 5) ? (i * 256 + t) : (1280 + t);
        int row = u / 136;
        int rem = u - row * 136;
        int p = rem >> 2, q = rem & 3;
        int cb = q ^ (p & 3) ^ ((p >> 2) & 3);
        int gh = h0 - 1 + row, gw = w0 - 1 + p;
        d.ok[i] = (u < 1360) && ((unsigned)gh < 256u) && ((unsigned)gw < 256u);
        d.goff[i]  = d.ok[i] ? (((uint)b * HW_ + (uint)gh * W_ + (uint)gw) * 32 + cb * 8) : 0u;
        d.goffT[i] = d.ok[i] ? (((uint)b * HW_ + (uint)gw * W_ + (uint)gh) * 32 + cb * 8) : 0u;
    }
}
// input stage: 5 full rounds + tail (waves 0,1). 6 DMAs for waves 0,1; 5 for 2,3.
__device__ __forceinline__ void stage_input(ushort* ibuf, const StageDescL& d,
                                            const ushort* __restrict__ inp,
                                            const ushort* __restrict__ zp,
                                            int t, int wid, bool tr) {
#pragma unroll
    for (int i = 0; i < 5; i++) {
        const ushort* src = d.ok[i] ? (inp + (tr ? d.goffT[i] : d.goff[i])) : zp;
        GLOAD_LDS16(src, ibuf + (size_t)(i * 256 + t) * 8);
    }
    if (wid < 2) {  // wave-uniform tail: slots 1280..1407
        const ushort* src = d.ok[5] ? (inp + (tr ? d.goffT[5] : d.goff[5])) : zp;
        GLOAD_LDS16(src, ibuf + (size_t)(1280 + t) * 8);
    }
}
// weight stage: contiguous 18 KB block copy. 4 full rounds + tail (waves 2,3).
// 4 DMAs for waves 0,1; 5 for waves 2,3  ->  total per wave = 10, uniform.
__device__ __forceinline__ void stage_wts(ushort* wbuf,
                                          const ushort* __restrict__ wsrc,
                                          int t, int wid) {
#pragma unroll
    for (int j = 0; j < 4; j++)
        GLOAD_LDS16(wsrc + (size_t)(j * 256 + t) * 8,
                    wbuf + (size_t)(j * 256 + t) * 8);
    if (wid >= 2)  // wave-uniform tail: slots 1024..1151
        GLOAD_LDS16(wsrc + (size_t)(1024 + t - 128) * 8,
                    wbuf + (size_t)(1024 + t - 128) * 8);
}

// MFMA phase over one staged chunk — PURE LDS + MFMA (zero VMEM ops, so no
// vmcnt wait can be emitted here and prefetch DMAs stay in flight).
__device__ __forceinline__ void mfma_chunk(const ushort* ibuf, const ushort* wbuf,
                                           int lco, int lhalf, int wid, int lane,
                                           floatx16& acc0, floatx16& acc1) {
#pragma unroll
    for (int half = 0; half < 2; half++) {
        short8 bf[9];
#pragma unroll
        for (int j = 0; j < 9; j++)
            bf[j] = *(const short8*)(wbuf + (size_t)((2 * j + half) * 64 + lane) * 8);
        const int cbr = half * 2 + lhalf;
#pragma unroll
        for (int kw = 0; kw < 3; kw++) {
            const int ww = lco + kw;
            const int cbs = cbr ^ (ww & 3) ^ ((ww >> 2) & 3);
            short8 a[4];
#pragma unroll
            for (int r = 0; r < 4; r++)
                a[r] = *(const short8*)(ibuf + (size_t)((wid * 2 + r) * 136 + (ww << 2) + cbs) * 8);
#pragma unroll
            for (int kh = 0; kh < 3; kh++) {
                acc0 = __builtin_amdgcn_mfma_f32_32x32x16_bf16(a[kh], bf[kh * 3 + kw], acc0, 0, 0, 0);
                acc1 = __builtin_amdgcn_mfma_f32_32x32x16_bf16(a[kh + 1], bf[kh * 3 + kw], acc1, 0, 0, 0);
            }
        }
    }
}

// ============ unified conv 3x3 (implicit GEMM, MFMA 32x32x16) =================
// T3/T4 pipeline (R4/R8 structure): weights staged to LDS with the input (one
// 10-DMA batch per chunk per wave), raw s_barrier + counted s_waitcnt vmcnt(10)
// keeps chunk ch+1's DMAs in flight across chunk ch's MFMA phase. For NCHUNK=4
// the odd chunks (g1/g3) are staged from TRANSPOSED tensors.
template<int NCHUNK, int EPI, bool RELU>
__global__ __launch_bounds__(256, (NCHUNK > 1) ? 2 : 4) void conv_mfma(
    const ushort* __restrict__ in0, const ushort* __restrict__ in1,
    const ushort* __restrict__ in2, const ushort* __restrict__ in3,
    const ushort* __restrict__ wB, const ushort* __restrict__ zp,
    ushort* __restrict__ outp, const float* __restrict__ aux_w,
    const float* __restrict__ aux_b) {
    constexpr int NBUF = (NCHUNK > 1) ? 2 : 1;
    __shared__ __align__(16) ushort smem[NBUF][BUF_SLOTS * 8];  // 40 KB / buf
    const int t = threadIdx.x;
    const int wid = t >> 6;
    const int lane = t & 63;
    const int lco = lane & 31, lhalf = lane >> 5;
    const int w0 = blockIdx.x * 32, h0 = blockIdx.y * 8, b = blockIdx.z;
    const ushort* ins[4] = {in0, in1, in2, in3};

    StageDescL d;
    make_descL(d, t, w0, h0, b);

    floatx16 acc0, acc1;
#pragma unroll
    for (int i = 0; i < 16; i++) { acc0[i] = 0.f; acc1[i] = 0.f; }

    stage_input(smem[0], d, ins[0], zp, t, wid, false);
    stage_wts(smem[0] + IN_SLOTS * 8, wB, t, wid);

    if constexpr (NCHUNK == 1) {
        __syncthreads();
        mfma_chunk(smem[0], smem[0] + IN_SLOTS * 8, lco, lhalf, wid, lane, acc0, acc1);
    } else {
#pragma unroll
        for (int ch = 0; ch < NCHUNK; ch++) {
            // barrier A: all waves' LDS reads of buf[(ch+1)&1] (chunk ch-1) done
            asm volatile("s_waitcnt lgkmcnt(0)" ::: "memory");
            __builtin_amdgcn_s_barrier();
            if (ch + 1 < NCHUNK) {
                stage_input(smem[(ch + 1) & 1], d, ins[ch + 1], zp, t, wid,
                            ((ch + 1) & 1) != 0);  // g1/g3 transposed
                stage_wts(smem[(ch + 1) & 1] + IN_SLOTS * 8,
                          wB + (size_t)(ch + 1) * 9216, t, wid);
                // own chunk-ch DMAs retired; the 10 newest (chunk ch+1) fly on
                asm volatile("s_waitcnt vmcnt(10)" ::: "memory");
            } else {
                asm volatile("s_waitcnt vmcnt(0)" ::: "memory");
            }
            __builtin_amdgcn_s_barrier();  // barrier B: buf[ch] staged everywhere
            mfma_chunk(smem[ch & 1], smem[ch & 1] + IN_SLOTS * 8,
                       lco, lhalf, wid, lane, acc0, acc1);
        }
    }

    if (EPI == 0) {
        // direct stores: per r the wave writes two contiguous 64B runs
#pragma unroll
        for (int r = 0; r < 16; r++) {
            int wl = (r & 3) + 8 * (r >> 2) + 4 * lhalf;
            float v0 = acc0[r], v1 = acc1[r];
            if (RELU) { v0 = fmaxf(v0, 0.f); v1 = fmaxf(v1, 0.f); }
            size_t p0 = (((size_t)b * HW_ + (h0 + wid * 2) * W_ + w0 + wl) * 32) + lco;
            outp[p0] = f2bf(v0);
            outp[p0 + (size_t)W_ * 32] = f2bf(v1);
        }
    } else {
        __syncthreads();  // smem free for epilogue tile [pix 256][stride 40]
        ushort* ep = &smem[0][0];
#pragma unroll
        for (int r = 0; r < 16; r++) {
            int wl = (r & 3) + 8 * (r >> 2) + 4 * lhalf;
            float v0 = acc0[r], v1 = acc1[r];
            if (RELU) { v0 = fmaxf(v0, 0.f); v1 = fmaxf(v1, 0.f); }
            int pix0 = (wid * 2) * 32 + wl;
            ep[(size_t)pix0 * 40 + lco] = f2bf(v0);
            ep[(size_t)(pix0 + 32) * 40 + lco] = f2bf(v1);
        }
        __syncthreads();
        const ushort* tp = ep + (size_t)t * 40;
        if (EPI == 1) {
            float xin[16];
            uint4 q0 = *(const uint4*)tp;
            uint4 q1 = *(const uint4*)(tp + 8);
            const ushort* u0 = (const ushort*)&q0;
            const ushort* u1 = (const ushort*)&q1;
#pragma unroll
            for (int j = 0; j < 8; j++) { xin[j] = bf2f(u0[j]); xin[8 + j] = bf2f(u1[j]); }
            size_t pix = (size_t)b * HW_ + (size_t)(h0 + (t >> 5)) * W_ + w0 + (t & 31);
#pragma unroll
            for (int g = 0; g < 4; g++) {
                float acc = aux_b[g];
#pragma unroll
                for (int ci = 0; ci < 16; ci++) acc = fmaf(xin[ci], aux_w[g * 16 + ci], acc);
                outp[(size_t)g * 8 * HW_ + pix] = f2bf(sigmoidf_(acc));
            }
        } else {
            float acc = 0.f;
#pragma unroll
            for (int q = 0; q < 4; q++) {
                uint4 qv = *(const uint4*)(tp + q * 8);
                const ushort* uq = (const ushort*)&qv;
#pragma unroll
                for (int j = 0; j < 8; j++) acc = fmaf(bf2f(uq[j]), aux_w[q * 8 + j], acc);
            }
            float* fo = (float*)outp;
            fo[(size_t)b * HW_ + (size_t)(h0 + (t >> 5)) * W_ + w0 + (t & 31)] = sigmoidf_(acc);
        }
    }
}

// ============ dual conv: one staging of xh -> feat (w_in) + a1 (aw1, relu) ====
__global__ __launch_bounds__(256, 2) void conv_dual(
    const ushort* __restrict__ in0, const ushort* __restrict__ wBa,
    const ushort* __restrict__ wBb, const ushort* __restrict__ zp,
    ushort* __restrict__ outA, ushort* __restrict__ outB) {
    __shared__ __align__(16) ushort smem[(IN_SLOTS + 2 * W_SLOTS) * 8];  // 58 KB
    const int t = threadIdx.x;
    const int wid = t >> 6;
    const int lane = t & 63;
    const int lco = lane & 31, lhalf = lane >> 5;
    const int w0 = blockIdx.x * 32, h0 = blockIdx.y * 8, b = blockIdx.z;

    StageDescL d;
    make_descL(d, t, w0, h0, b);

    floatx16 accA0, accA1, accB0, accB1;
#pragma unroll
    for (int i = 0; i < 16; i++) { accA0[i] = 0.f; accA1[i] = 0.f; accB0[i] = 0.f; accB1[i] = 0.f; }

    stage_input(smem, d, in0, zp, t, wid, false);
    stage_wts(smem + IN_SLOTS * 8, wBa, t, wid);
    stage_wts(smem + (IN_SLOTS + W_SLOTS) * 8, wBb, t, wid);
    __syncthreads();
    mfma_chunk(smem, smem + IN_SLOTS * 8, lco, lhalf, wid, lane, accA0, accA1);
    mfma_chunk(smem, smem + (IN_SLOTS + W_SLOTS) * 8, lco, lhalf, wid, lane, accB0, accB1);

#pragma unroll
    for (int r = 0; r < 16; r++) {
        int wl = (r & 3) + 8 * (r >> 2) + 4 * lhalf;
        size_t p0 = (((size_t)b * HW_ + (h0 + wid * 2) * W_ + w0 + wl) * 32) + lco;
        outA[p0] = f2bf(accA0[r]);
        outA[p0 + (size_t)W_ * 32] = f2bf(accA1[r]);
        outB[p0] = f2bf(fmaxf(accB0[r], 0.f));
        outB[p0 + (size_t)W_ * 32] = f2bf(fmaxf(accB1[r], 0.f));
    }
}

// ============ segmented IRNN scan, vectorized 8ch/thread (R6 + transposed) ====
// Fused fwd+bwd per block over the same physical window (R6, cache reuse).
// NEW: horizontal (VERT=0) outputs are written TRANSPOSED (gT[w*W+h]) so the
// write stream is contiguous 1 KB/wave like the vertical axis — the 64B @
// 16KB-stride scatter was the HBM write-efficiency limiter. Reads (feat,
// wmap) keep original orientation. conv<4> stages g1/g3 via goffT.
// 8 segments of 32 + 8-step warmup (0.2^8 ~ 2.6e-6, validated in R5).
template<int VERT>
__device__ __forceinline__ void scan_body(
    const ushort* __restrict__ feat, const float* __restrict__ alpha,
    const ushort* __restrict__ wmapT, ushort* __restrict__ gfwd,
    ushort* __restrict__ gbwd, int gf, int gb, int dir, int seg,
    int cgp, int b, int t) {
    const int cg = t & 3;
    const int col = cgp * 64 + (t >> 2);
    const int c0 = cg * 8;

    float a[8];
#pragma unroll
    for (int j = 0; j < 8; j++) a[j] = alpha[c0 + j];

    const ushort* wplane = wmapT + (size_t)(dir ? gb : gf) * 8 * HW_ + (size_t)b * HW_;
    ushort* gout = dir ? gbwd : gfwd;

    const int main0 = seg * 32;
    const int start = (seg == 0) ? 0 : main0 - 8;
    const int cnt = main0 - start + 32;

    // read index: original orientation (feat, wmap)
    auto pixR = [&](int p) -> size_t {
        int phys = dir ? 255 - p : p;
        return VERT ? ((size_t)phys * W_ + col) : ((size_t)col * W_ + phys);
    };
    // write index: coalesced for BOTH axes (horizontal stores transposed)
    auto pixW = [&](int p) -> size_t {
        int phys = dir ? 255 - p : p;
        return (size_t)phys * W_ + col;
    };

    uint4 xv[4];
    ushort wv[4];
#pragma unroll
    for (int k = 0; k < 4; k++) {
        size_t pix = pixR(start + k);
        xv[k] = *(const uint4*)(feat + ((size_t)b * HW_ + pix) * 32 + c0);
        wv[k] = wplane[pix];
    }
    float prev[8];
#pragma unroll
    for (int j = 0; j < 8; j++) prev[j] = 0.f;

    for (int i = 0; i < cnt; i += 4) {
#pragma unroll
        for (int k = 0; k < 4; k++) {
            const int p = start + i + k;
            uint4 xcur = xv[k];
            ushort wcur = wv[k];
            if (i + k + 4 < cnt) {
                size_t pix = pixR(p + 4);
                xv[k] = *(const uint4*)(feat + ((size_t)b * HW_ + pix) * 32 + c0);
                wv[k] = wplane[pix];
            }
            const ushort* xu = (const ushort*)&xcur;
            if (p >= main0) {
                float wmv = bf2f(wcur);
                ushort o[8];
#pragma unroll
                for (int j = 0; j < 8; j++) {
                    float cur = fmaxf(fmaf(a[j], prev[j], bf2f(xu[j])), 0.f);
                    prev[j] = cur;
                    o[j] = f2bf(cur * wmv);
                }
                *(uint4*)(gout + ((size_t)b * HW_ + pixW(p)) * 32 + c0) = *(const uint4*)o;
            } else {
#pragma unroll
                for (int j = 0; j < 8; j++)
                    prev[j] = fmaxf(fmaf(a[j], prev[j], bf2f(xu[j])), 0.f);
            }
        }
    }
}

__global__ __launch_bounds__(256) void scan_both(
    const ushort* __restrict__ feat, const float* __restrict__ alpha,
    const ushort* __restrict__ wmapT, ushort* __restrict__ g0,
    ushort* __restrict__ g1, ushort* __restrict__ g2, ushort* __restrict__ g3) {
    const int bx = blockIdx.x & 255;
    const int cgp = bx & 3;
    const int seg = (bx >> 2) & 7;
    const int b = bx >> 5;
    const int t = threadIdx.x;
    if (blockIdx.x < 256) {
        // vertical axis: fwd seg s, then bwd seg 7-s (same phys rows)
        scan_body<1>(feat, alpha, wmapT, g0, g2, 0, 2, 0, seg, cgp, b, t);
        scan_body<1>(feat, alpha, wmapT, g0, g2, 0, 2, 1, 7 - seg, cgp, b, t);
    } else {
        scan_body<0>(feat, alpha, wmapT, g1, g3, 1, 3, 0, seg, cgp, b, t);
        scan_body<0>(feat, alpha, wmapT, g1, g3, 1, 3, 1, 7 - seg, cgp, b, t);
    }
}

extern "C" void kernel_launch(void* const* d_in, const int* in_sizes, int n_in,
                              void* d_out, int out_size, void* d_ws, size_t ws_size,
                              hipStream_t stream) {
    const float* x      = (const float*)d_in[0];
    const float* alpha1 = (const float*)d_in[1];
    const float* alpha2 = (const float*)d_in[2];
    const float* w_in   = (const float*)d_in[3];
    const float* w2     = (const float*)d_in[4];
    const float* w3     = (const float*)d_in[5];
    const float* aw1    = (const float*)d_in[6];
    const float* aw2    = (const float*)d_in[7];
    const float* aw3    = (const float*)d_in[8];
    const float* ab3    = (const float*)d_in[9];
    const float* wout   = (const float*)d_in[10];
    float* out = (float*)d_out;

    // ---- workspace carve (ushorts), ~206 MB ----
    const size_t TEN = (size_t)8 * HW_ * 32;
    ushort* p = (ushort*)d_ws;
    ushort* xh    = p; p += TEN;
    ushort* feat  = p; p += TEN;
    ushort* g0    = p; p += TEN;
    ushort* g1    = p; p += TEN;
    ushort* g2    = p; p += TEN;
    ushort* g3    = p; p += TEN;
    ushort* wmapT = p; p += (size_t)4 * 8 * HW_;
    ushort* w_inB = p; p += 9216;
    ushort* w2B   = p; p += 36864;
    ushort* w3B   = p; p += 36864;
    ushort* aw1B  = p; p += 9216;
    ushort* aw2B  = p; p += 9216;
    ushort* zp    = p; p += 64;
    ushort* a1z   = g1;  // attention intermediate overlays g1 (dead until scans)

    prep_weights<<<396, 256, 0, stream>>>(w_in, w2, w3, aw1, aw2,
                                          w_inB, w2B, w3B, aw1B, aw2B, zp);
    transform_x<<<dim3(4, 256, 8), 256, 0, stream>>>(x, xh);

    dim3 gconv(8, 32, 8);  // 32x8 tiles

    // trunk conv + first attention conv share one staging pass of xh
    conv_dual<<<gconv, 256, 0, stream>>>(xh, w_inB, aw1B, zp, feat, a1z);
    // second attention conv with fused att1x1+sigmoid -> wmapT planes
    conv_mfma<1, 1, true><<<gconv, 256, 0, stream>>>(a1z, a1z, a1z, a1z, aw2B, zp,
                                                     wmapT, aw3, ab3);

    // round 1 scans (both axes + both dirs fused, one dispatch)
    scan_both<<<512, 256, 0, stream>>>(feat, alpha1, wmapT, g0, g1, g2, g3);

    conv_mfma<4, 0, false><<<gconv, 256, 0, stream>>>(g0, g1, g2, g3, w2B, zp,
                                                      feat, nullptr, nullptr);

    // round 2 scans
    scan_both<<<512, 256, 0, stream>>>(feat, alpha2, wmapT, g0, g1, g2, g3);

    // final conv with fused out1x1+sigmoid -> fp32 out
    conv_mfma<4, 2, true><<<gconv, 256, 0, stream>>>(g0, g1, g2, g3, w3B, zp,
                                                     (ushort*)out, wout, nullptr);
}